// Round 1
// baseline (127.232 us; speedup 1.0000x reference)
//
#include <hip/hip_runtime.h>
#include <math.h>

// SIDIS forward: one 64-lane wave per event, lane = Ogata node.
// Gathers are divergent-but-cached (grids are 2 MB each -> L2 resident).

namespace {
constexpr int   kNB    = 256;
constexpr int   kNX    = 256;
constexpr float kLXMIN = -9.210340371976182f;   // log(1e-4)
constexpr float kLBMIN = -6.907755278982137f;   // log(1e-3)
constexpr float kLBMAX =  3.912023005428146f;   // log(50)
constexpr float kG2    = 0.12f;
constexpr float kM2    = 0.8803f;
constexpr float kSmM2  = 140.0f - 0.8803f;      // S_MAND - M2
constexpr float kALPHA0 = 1.0f / 137.035999f;
constexpr float kME2   = 0.000511f * 0.000511f;
}

__global__ __launch_bounds__(256) void sidis_fwd(
    const float* __restrict__ events,
    const float* __restrict__ pdfg,
    const float* __restrict__ ffg,
    const float* __restrict__ ogx,
    const float* __restrict__ ogw,
    const float* __restrict__ fnp,
    float* __restrict__ out)
{
    const int lane = threadIdx.x & 63;
    const int ev   = (blockIdx.x << 2) + (threadIdx.x >> 6);   // 4 waves/block

    // Event record broadcast (same 16B for all 64 lanes -> L1 broadcast).
    const float4 e = reinterpret_cast<const float4*>(events)[ev];
    const float x = e.x, PhT = e.y, Q = e.z, z = e.w;
    const float qT = PhT / z;
    const float Q2 = Q * Q;

    // fnp-derived scalars (wave-uniform, tiny).
    const float lam_p = log1pf(__expf(fnp[0]));
    const float lam_f = log1pf(__expf(fnp[1]));
    const float sig2  = 1.0f / (1.0f + __expf(-fnp[2]));
    const float sig3  = 1.0f / (1.0f + __expf(-fnp[3]));

    // Per-lane Ogata node.
    const float u_k = ogx[lane];
    const float w_k = ogw[lane];
    const float bT  = u_k / qT;
    const float lb  = __logf(bT);

    float fb = (lb - kLBMIN) * ((float)(kNB - 1) / (kLBMAX - kLBMIN));
    fb = fminf(fmaxf(fb, 0.0f), (float)(kNB - 1) - 1e-4f);
    const int   j0 = (int)fb;
    const float tb = fb - (float)j0;

    const float lx = __logf(x);
    float fxp = (lx - kLXMIN) * ((float)(kNX - 1) / (0.0f - kLXMIN));
    fxp = fminf(fmaxf(fxp, 0.0f), (float)(kNX - 1) - 1e-4f);
    const int   i0p = (int)fxp;
    const float txp = fxp - (float)i0p;

    const float lz = __logf(z);
    float fxf = (lz - kLXMIN) * ((float)(kNX - 1) / (0.0f - kLXMIN));
    fxf = fminf(fmaxf(fxf, 0.0f), (float)(kNX - 1) - 1e-4f);
    const int   i0f = (int)fxf;
    const float txf = fxf - (float)i0f;

    const float* pbase = pdfg + i0p * kNB + j0;
    const float* fbase = ffg  + i0f * kNB + j0;

    const float E2a[8] = {4.f/9, 1.f/9, 1.f/9, 4.f/9, 4.f/9, 1.f/9, 1.f/9, 4.f/9};

    float s = 0.0f;
    #pragma unroll
    for (int f = 0; f < 8; ++f) {
        const float* gp = pbase + f * (kNX * kNB);
        const float p00 = gp[0], p01 = gp[1], p10 = gp[kNB], p11 = gp[kNB + 1];
        const float* gf = fbase + f * (kNX * kNB);
        const float q00 = gf[0], q01 = gf[1], q10 = gf[kNB], q11 = gf[kNB + 1];
        const float pv = (1.0f - txp) * ((1.0f - tb) * p00 + tb * p01)
                       +          txp * ((1.0f - tb) * p10 + tb * p11);
        const float fv = (1.0f - txf) * ((1.0f - tb) * q00 + tb * q01)
                       +          txf * ((1.0f - tb) * q10 + tb * q11);
        s += E2a[f] * pv * fv;
    }

    // Fused damping: evo2 * f_pdf * f_ff in a single exp.
    const float bT2 = bT * bT;
    const float lQ2 = __logf(Q2);                 // Q20 == 1
    const float expo = -bT2 * (kG2 * lQ2
                               + lam_p * (1.0f - sig2 * lx)        // log(1/x) = -lx
                               + lam_f * (1.0f + sig3) / (z * z));
    float val = s * __expf(expo) * w_k;

    // Wave-64 reduction over Ogata nodes.
    #pragma unroll
    for (int off = 32; off > 0; off >>= 1)
        val += __shfl_down(val, off, 64);

    if (lane == 0) {
        const float FUUT  = val / (qT * qT);
        const float alpha = kALPHA0 /
            (1.0f - kALPHA0 / (3.0f * (float)M_PI) * (lQ2 - logf(kME2)));
        const float gamma = 2.0f * kM2 * x / Q;
        const float y     = Q2 / (x * kSmM2);
        const float g2y2  = 0.25f * gamma * gamma * y * y;
        const float eps   = (1.0f - y - g2y2) /
                            (1.0f - y + 0.5f * y * y + g2y2);
        const float pre   = 8.0f * (float)(M_PI * M_PI) * alpha * alpha
                          * z * z * qT / x / (Q2 * Q)
                          * y * y * 0.5f / (1.0f - eps)
                          * (1.0f + gamma * gamma / (2.0f * x));
        out[ev] = pre * FUUT;
    }
}

extern "C" void kernel_launch(void* const* d_in, const int* in_sizes, int n_in,
                              void* d_out, int out_size, void* d_ws, size_t ws_size,
                              hipStream_t stream) {
    const float* events = (const float*)d_in[0];   // (65536, 4)
    const float* pdfg   = (const float*)d_in[1];   // (8, 256, 256)
    const float* ffg    = (const float*)d_in[2];   // (8, 256, 256)
    const float* ogx    = (const float*)d_in[3];   // (64,)
    const float* ogw    = (const float*)d_in[4];   // (64,)
    const float* fnp    = (const float*)d_in[5];   // (4,)
    float* out = (float*)d_out;                    // (65536,) fp32

    const int nev = in_sizes[0] / 4;               // 65536
    dim3 block(256);                               // 4 waves = 4 events / block
    dim3 grid(nev / 4);
    sidis_fwd<<<grid, block, 0, stream>>>(events, pdfg, ffg, ogx, ogw, fnp, out);
}

// Round 2
// 122.260 us; speedup vs baseline: 1.0407x; 1.0407x over previous
//
#include <hip/hip_runtime.h>
#include <math.h>

// SIDIS forward, round 2: flavor-innermost grid repack into d_ws, then one
// 64-lane wave per event (lane = Ogata node) reading 8 flavors per corner as
// two dwordx4 loads with immediate offsets. Packed-f32 interp math.

namespace {
constexpr int   kNB    = 256;
constexpr int   kNX    = 256;
constexpr float kLXMIN = -9.210340371976182f;   // log(1e-4)
constexpr float kLBMIN = -6.907755278982137f;   // log(1e-3)
constexpr float kLBMAX =  3.912023005428146f;   // log(50)
constexpr float kG2    = 0.12f;
constexpr float kM2    = 0.8803f;
constexpr float kSmM2  = 140.0f - 0.8803f;      // S_MAND - M2
constexpr float kALPHA0 = 1.0f / 137.035999f;
constexpr float kME2   = 0.000511f * 0.000511f;
constexpr int   kGridElems = kNX * kNB;          // 65536 per flavor
}

typedef float f32x4 __attribute__((ext_vector_type(4)));

// Repack (8, NX, NB) -> (NX*NB, 8): per (i,j) cell, 8 flavors contiguous (32 B).
__global__ __launch_bounds__(256) void interleave_grids(
    const float* __restrict__ pdfg, const float* __restrict__ ffg,
    float* __restrict__ wpdf, float* __restrict__ wff)
{
    const int idx = blockIdx.x * 256 + threadIdx.x;   // i*256 + j
    float p[8], q[8];
    #pragma unroll
    for (int f = 0; f < 8; ++f) {
        p[f] = pdfg[f * kGridElems + idx];
        q[f] = ffg [f * kGridElems + idx];
    }
    f32x4* dp = reinterpret_cast<f32x4*>(wpdf + idx * 8);
    dp[0] = (f32x4){p[0], p[1], p[2], p[3]};
    dp[1] = (f32x4){p[4], p[5], p[6], p[7]};
    f32x4* dq = reinterpret_cast<f32x4*>(wff + idx * 8);
    dq[0] = (f32x4){q[0], q[1], q[2], q[3]};
    dq[1] = (f32x4){q[4], q[5], q[6], q[7]};
}

__device__ __forceinline__ float warp_prefix_common(
    float x, float PhT, float Q, float z, float qT, float Q2,
    float val, int lane, float lQ2, float* outp)
{
    return 0.f; // unused placeholder
}

__global__ __launch_bounds__(256) void sidis_fwd_packed(
    const float* __restrict__ events,
    const float* __restrict__ wpdf,
    const float* __restrict__ wff,
    const float* __restrict__ ogx,
    const float* __restrict__ ogw,
    const float* __restrict__ fnp,
    float* __restrict__ out)
{
    const int lane = threadIdx.x & 63;
    const int ev   = (blockIdx.x << 2) + (threadIdx.x >> 6);   // 4 waves/block

    const float4 e = reinterpret_cast<const float4*>(events)[ev];
    const float x = e.x, PhT = e.y, Q = e.z, z = e.w;
    const float qT = PhT / z;
    const float Q2 = Q * Q;

    const float lam_p = log1pf(__expf(fnp[0]));
    const float lam_f = log1pf(__expf(fnp[1]));
    const float sig2  = 1.0f / (1.0f + __expf(-fnp[2]));
    const float sig3  = 1.0f / (1.0f + __expf(-fnp[3]));

    const float u_k = ogx[lane];
    const float w_k = ogw[lane];
    const float bT  = u_k / qT;
    const float lb  = __logf(bT);

    float fb = (lb - kLBMIN) * ((float)(kNB - 1) / (kLBMAX - kLBMIN));
    fb = fminf(fmaxf(fb, 0.0f), (float)(kNB - 1) - 1e-4f);
    const int   j0 = (int)fb;
    const float tb = fb - (float)j0;

    const float lx = __logf(x);
    float fxp = (lx - kLXMIN) * ((float)(kNX - 1) / (0.0f - kLXMIN));
    fxp = fminf(fmaxf(fxp, 0.0f), (float)(kNX - 1) - 1e-4f);
    const int   i0p = (int)fxp;
    const float txp = fxp - (float)i0p;

    const float lz = __logf(z);
    float fxf = (lz - kLXMIN) * ((float)(kNX - 1) / (0.0f - kLXMIN));
    fxf = fminf(fmaxf(fxf, 0.0f), (float)(kNX - 1) - 1e-4f);
    const int   i0f = (int)fxf;
    const float txf = fxf - (float)i0f;

    // Bilinear corner weights (shared across flavors).
    const float omtb = 1.0f - tb;
    const float w00p = (1.0f - txp) * omtb, w01p = (1.0f - txp) * tb;
    const float w10p = txp * omtb,          w11p = txp * tb;
    const float w00f = (1.0f - txf) * omtb, w01f = (1.0f - txf) * tb;
    const float w10f = txf * omtb,          w11f = txf * tb;

    // PDF: rows i0p and i0p+1; per row 16 floats (j0,j0+1 × 8 flavors) = 64 B.
    const f32x4* pr0 = reinterpret_cast<const f32x4*>(wpdf + (i0p * kNB + j0) * 8);
    const f32x4* pr1 = pr0 + (kNB * 8 / 4);            // +2048 floats
    const f32x4 a0 = pr0[0], a1 = pr0[1], b0 = pr0[2], b1 = pr0[3];
    const f32x4 c0 = pr1[0], c1 = pr1[1], d0 = pr1[2], d1 = pr1[3];

    // FF: rows i0f and i0f+1.
    const f32x4* fr0 = reinterpret_cast<const f32x4*>(wff + (i0f * kNB + j0) * 8);
    const f32x4* fr1 = fr0 + (kNB * 8 / 4);
    const f32x4 ea0 = fr0[0], ea1 = fr0[1], eb0 = fr0[2], eb1 = fr0[3];
    const f32x4 ec0 = fr1[0], ec1 = fr1[1], ed0 = fr1[2], ed1 = fr1[3];

    const f32x4 pv_lo = w00p * a0 + w01p * b0 + w10p * c0 + w11p * d0;
    const f32x4 pv_hi = w00p * a1 + w01p * b1 + w10p * c1 + w11p * d1;
    const f32x4 fv_lo = w00f * ea0 + w01f * eb0 + w10f * ec0 + w11f * ed0;
    const f32x4 fv_hi = w00f * ea1 + w01f * eb1 + w10f * ec1 + w11f * ed1;

    // E2 lo half == hi half == {4/9, 1/9, 1/9, 4/9}.
    const f32x4 e2 = (f32x4){4.f/9.f, 1.f/9.f, 1.f/9.f, 4.f/9.f};
    const f32x4 acc = e2 * (pv_lo * fv_lo + pv_hi * fv_hi);
    const float s = (acc.x + acc.y) + (acc.z + acc.w);

    // Fused damping: evo2 * f_pdf * f_ff in one exp.
    const float bT2 = bT * bT;
    const float lQ2 = __logf(Q2);                      // Q20 == 1
    const float expo = -bT2 * (kG2 * lQ2
                               + lam_p * (1.0f - sig2 * lx)
                               + lam_f * (1.0f + sig3) / (z * z));
    float val = s * __expf(expo) * w_k;

    #pragma unroll
    for (int off = 32; off > 0; off >>= 1)
        val += __shfl_down(val, off, 64);

    if (lane == 0) {
        const float FUUT  = val / (qT * qT);
        const float alpha = kALPHA0 /
            (1.0f - kALPHA0 / (3.0f * (float)M_PI) * (lQ2 - logf(kME2)));
        const float gamma = 2.0f * kM2 * x / Q;
        const float y     = Q2 / (x * kSmM2);
        const float g2y2  = 0.25f * gamma * gamma * y * y;
        const float eps   = (1.0f - y - g2y2) /
                            (1.0f - y + 0.5f * y * y + g2y2);
        const float pre   = 8.0f * (float)(M_PI * M_PI) * alpha * alpha
                          * z * z * qT / x / (Q2 * Q)
                          * y * y * 0.5f / (1.0f - eps)
                          * (1.0f + gamma * gamma / (2.0f * x));
        out[ev] = pre * FUUT;
    }
}

// ---- Round-1 fallback (used only if ws_size < 4 MB) ----
__global__ __launch_bounds__(256) void sidis_fwd_direct(
    const float* __restrict__ events,
    const float* __restrict__ pdfg,
    const float* __restrict__ ffg,
    const float* __restrict__ ogx,
    const float* __restrict__ ogw,
    const float* __restrict__ fnp,
    float* __restrict__ out)
{
    const int lane = threadIdx.x & 63;
    const int ev   = (blockIdx.x << 2) + (threadIdx.x >> 6);

    const float4 e = reinterpret_cast<const float4*>(events)[ev];
    const float x = e.x, PhT = e.y, Q = e.z, z = e.w;
    const float qT = PhT / z;
    const float Q2 = Q * Q;

    const float lam_p = log1pf(__expf(fnp[0]));
    const float lam_f = log1pf(__expf(fnp[1]));
    const float sig2  = 1.0f / (1.0f + __expf(-fnp[2]));
    const float sig3  = 1.0f / (1.0f + __expf(-fnp[3]));

    const float u_k = ogx[lane];
    const float w_k = ogw[lane];
    const float bT  = u_k / qT;
    const float lb  = __logf(bT);

    float fb = (lb - kLBMIN) * ((float)(kNB - 1) / (kLBMAX - kLBMIN));
    fb = fminf(fmaxf(fb, 0.0f), (float)(kNB - 1) - 1e-4f);
    const int   j0 = (int)fb;
    const float tb = fb - (float)j0;

    const float lx = __logf(x);
    float fxp = (lx - kLXMIN) * ((float)(kNX - 1) / (0.0f - kLXMIN));
    fxp = fminf(fmaxf(fxp, 0.0f), (float)(kNX - 1) - 1e-4f);
    const int   i0p = (int)fxp;
    const float txp = fxp - (float)i0p;

    const float lz = __logf(z);
    float fxf = (lz - kLXMIN) * ((float)(kNX - 1) / (0.0f - kLXMIN));
    fxf = fminf(fmaxf(fxf, 0.0f), (float)(kNX - 1) - 1e-4f);
    const int   i0f = (int)fxf;
    const float txf = fxf - (float)i0f;

    const float* pbase = pdfg + i0p * kNB + j0;
    const float* fbase = ffg  + i0f * kNB + j0;
    const float E2a[8] = {4.f/9, 1.f/9, 1.f/9, 4.f/9, 4.f/9, 1.f/9, 1.f/9, 4.f/9};

    float s = 0.0f;
    #pragma unroll
    for (int f = 0; f < 8; ++f) {
        const float* gp = pbase + f * kGridElems;
        const float p00 = gp[0], p01 = gp[1], p10 = gp[kNB], p11 = gp[kNB + 1];
        const float* gf = fbase + f * kGridElems;
        const float q00 = gf[0], q01 = gf[1], q10 = gf[kNB], q11 = gf[kNB + 1];
        const float pv = (1.0f - txp) * ((1.0f - tb) * p00 + tb * p01)
                       +          txp * ((1.0f - tb) * p10 + tb * p11);
        const float fv = (1.0f - txf) * ((1.0f - tb) * q00 + tb * q01)
                       +          txf * ((1.0f - tb) * q10 + tb * q11);
        s += E2a[f] * pv * fv;
    }

    const float bT2 = bT * bT;
    const float lQ2 = __logf(Q2);
    const float expo = -bT2 * (kG2 * lQ2
                               + lam_p * (1.0f - sig2 * lx)
                               + lam_f * (1.0f + sig3) / (z * z));
    float val = s * __expf(expo) * w_k;

    #pragma unroll
    for (int off = 32; off > 0; off >>= 1)
        val += __shfl_down(val, off, 64);

    if (lane == 0) {
        const float FUUT  = val / (qT * qT);
        const float alpha = kALPHA0 /
            (1.0f - kALPHA0 / (3.0f * (float)M_PI) * (lQ2 - logf(kME2)));
        const float gamma = 2.0f * kM2 * x / Q;
        const float y     = Q2 / (x * kSmM2);
        const float g2y2  = 0.25f * gamma * gamma * y * y;
        const float eps   = (1.0f - y - g2y2) /
                            (1.0f - y + 0.5f * y * y + g2y2);
        const float pre   = 8.0f * (float)(M_PI * M_PI) * alpha * alpha
                          * z * z * qT / x / (Q2 * Q)
                          * y * y * 0.5f / (1.0f - eps)
                          * (1.0f + gamma * gamma / (2.0f * x));
        out[ev] = pre * FUUT;
    }
}

extern "C" void kernel_launch(void* const* d_in, const int* in_sizes, int n_in,
                              void* d_out, int out_size, void* d_ws, size_t ws_size,
                              hipStream_t stream) {
    const float* events = (const float*)d_in[0];   // (65536, 4)
    const float* pdfg   = (const float*)d_in[1];   // (8, 256, 256)
    const float* ffg    = (const float*)d_in[2];   // (8, 256, 256)
    const float* ogx    = (const float*)d_in[3];   // (64,)
    const float* ogw    = (const float*)d_in[4];   // (64,)
    const float* fnp    = (const float*)d_in[5];   // (4,)
    float* out = (float*)d_out;

    const int nev = in_sizes[0] / 4;               // 65536
    const size_t grid_bytes = (size_t)kGridElems * 8 * sizeof(float); // 2 MB

    if (ws_size >= 2 * grid_bytes) {
        float* wpdf = (float*)d_ws;
        float* wff  = wpdf + (size_t)kGridElems * 8;
        interleave_grids<<<kGridElems / 256, 256, 0, stream>>>(pdfg, ffg, wpdf, wff);
        sidis_fwd_packed<<<nev / 4, 256, 0, stream>>>(events, wpdf, wff,
                                                      ogx, ogw, fnp, out);
    } else {
        sidis_fwd_direct<<<nev / 4, 256, 0, stream>>>(events, pdfg, ffg,
                                                      ogx, ogw, fnp, out);
    }
}

// Round 3
// 111.552 us; speedup vs baseline: 1.1406x; 1.0960x over previous
//
#include <hip/hip_runtime.h>
#include <math.h>

// SIDIS forward, round 3: flavor-innermost repack (round 2) + hoisted
// transcendentals/divides. Precompute kernel writes fnp-derived constants and
// per-Ogata-node constants; main kernel has 4 wave-uniform logs + 1 exp and
// zero slow divides (v_rcp_f32 everywhere).

namespace {
constexpr int   kNB    = 256;
constexpr int   kNX    = 256;
constexpr float kLXMIN = -9.210340371976182f;   // log(1e-4)
constexpr float kLBMIN = -6.907755278982137f;   // log(1e-3)
constexpr float kLBMAX =  3.912023005428146f;   // log(50)
constexpr float kScaleB = (float)(kNB - 1) / (kLBMAX - kLBMIN);
constexpr float kScaleX = (float)(kNX - 1) / (0.0f - kLXMIN);
constexpr float kG2    = 0.12f;
constexpr float kM2    = 0.8803f;
constexpr float kSmM2  = 140.0f - 0.8803f;      // S_MAND - M2
constexpr float kALPHA0 = 1.0f / 137.035999f;
constexpr float kME2   = 0.000511f * 0.000511f;
constexpr int   kGridElems = kNX * kNB;          // 65536 per flavor
}

typedef float f32x4 __attribute__((ext_vector_type(4)));

__device__ __forceinline__ float frcp(float x) { return __builtin_amdgcn_rcpf(x); }

// Repack (8, NX, NB) -> (NX*NB, 8): per (i,j) cell, 8 flavors contiguous (32 B).
__global__ __launch_bounds__(256) void interleave_grids(
    const float* __restrict__ pdfg, const float* __restrict__ ffg,
    float* __restrict__ wpdf, float* __restrict__ wff)
{
    const int idx = blockIdx.x * 256 + threadIdx.x;   // i*256 + j
    float p[8], q[8];
    #pragma unroll
    for (int f = 0; f < 8; ++f) {
        p[f] = pdfg[f * kGridElems + idx];
        q[f] = ffg [f * kGridElems + idx];
    }
    f32x4* dp = reinterpret_cast<f32x4*>(wpdf + idx * 8);
    dp[0] = (f32x4){p[0], p[1], p[2], p[3]};
    dp[1] = (f32x4){p[4], p[5], p[6], p[7]};
    f32x4* dq = reinterpret_cast<f32x4*>(wff + idx * 8);
    dq[0] = (f32x4){q[0], q[1], q[2], q[3]};
    dq[1] = (f32x4){q[4], q[5], q[6], q[7]};
}

// Hoisted constants: knode[k] = {(log u_k - LBMIN)*scaleB, W_k, u_k^2, 0};
// cons = {lam_p, lam_p*sig2, lam_f*(1+sig3), 0}.
__global__ __launch_bounds__(64) void precompute_consts(
    const float* __restrict__ ogx, const float* __restrict__ ogw,
    const float* __restrict__ fnp,
    float* __restrict__ knode, float* __restrict__ cons)
{
    const int t = threadIdx.x;                        // 64 threads
    const float u = ogx[t];
    f32x4* kn = reinterpret_cast<f32x4*>(knode);
    kn[t] = (f32x4){(logf(u) - kLBMIN) * kScaleB, ogw[t], u * u, 0.0f};
    if (t == 0) {
        const float lam_p = log1pf(expf(fnp[0]));
        const float lam_f = log1pf(expf(fnp[1]));
        const float sig2  = 1.0f / (1.0f + expf(-fnp[2]));
        const float sig3  = 1.0f / (1.0f + expf(-fnp[3]));
        f32x4* c = reinterpret_cast<f32x4*>(cons);
        c[0] = (f32x4){lam_p, lam_p * sig2, lam_f * (1.0f + sig3), 0.0f};
    }
}

__global__ __launch_bounds__(256) void sidis_fwd3(
    const float* __restrict__ events,
    const float* __restrict__ wpdf,
    const float* __restrict__ wff,
    const float* __restrict__ knode,
    const float* __restrict__ cons,
    float* __restrict__ out)
{
    const int lane = threadIdx.x & 63;
    const int ev   = (blockIdx.x << 2) + (threadIdx.x >> 6);   // 4 waves/block

    const float4 e  = reinterpret_cast<const float4*>(events)[ev];
    const f32x4  kn = reinterpret_cast<const f32x4*>(knode)[lane];
    const f32x4  cn = reinterpret_cast<const f32x4*>(cons)[0];

    const float x = e.x, PhT = e.y, Q = e.z, z = e.w;
    const float rz  = frcp(z);
    const float qT  = PhT * rz;
    const float rqT = z * frcp(PhT);
    const float Q2  = Q * Q;

    // Wave-uniform logs (4 per wave total).
    const float lqT = __logf(qT);
    const float lx  = __logf(x);
    const float lz  = __logf(z);
    const float lQ2 = 2.0f * __logf(Q);

    // Per-lane b-coordinate: one FMA.
    float fb = fmaf(-lqT, kScaleB, kn.x);
    fb = fminf(fmaxf(fb, 0.0f), (float)(kNB - 1) - 1e-4f);
    const int   j0 = (int)fb;
    const float tb = fb - (float)j0;

    float fxp = (lx - kLXMIN) * kScaleX;
    fxp = fminf(fmaxf(fxp, 0.0f), (float)(kNX - 1) - 1e-4f);
    const int   i0p = (int)fxp;
    const float txp = fxp - (float)i0p;

    float fxf = (lz - kLXMIN) * kScaleX;
    fxf = fminf(fmaxf(fxf, 0.0f), (float)(kNX - 1) - 1e-4f);
    const int   i0f = (int)fxf;
    const float txf = fxf - (float)i0f;

    const float omtb = 1.0f - tb;
    const float w00p = (1.0f - txp) * omtb, w01p = (1.0f - txp) * tb;
    const float w10p = txp * omtb,          w11p = txp * tb;
    const float w00f = (1.0f - txf) * omtb, w01f = (1.0f - txf) * tb;
    const float w10f = txf * omtb,          w11f = txf * tb;

    // PDF rows i0p / i0p+1: 16 floats each (j0, j0+1 x 8 flavors).
    const f32x4* pr0 = reinterpret_cast<const f32x4*>(wpdf + (i0p * kNB + j0) * 8);
    const f32x4* pr1 = pr0 + (kNB * 8 / 4);
    const f32x4 a0 = pr0[0], a1 = pr0[1], b0 = pr0[2], b1 = pr0[3];
    const f32x4 c0 = pr1[0], c1 = pr1[1], d0 = pr1[2], d1 = pr1[3];

    const f32x4* fr0 = reinterpret_cast<const f32x4*>(wff + (i0f * kNB + j0) * 8);
    const f32x4* fr1 = fr0 + (kNB * 8 / 4);
    const f32x4 ea0 = fr0[0], ea1 = fr0[1], eb0 = fr0[2], eb1 = fr0[3];
    const f32x4 ec0 = fr1[0], ec1 = fr1[1], ed0 = fr1[2], ed1 = fr1[3];

    const f32x4 pv_lo = w00p * a0 + w01p * b0 + w10p * c0 + w11p * d0;
    const f32x4 pv_hi = w00p * a1 + w01p * b1 + w10p * c1 + w11p * d1;
    const f32x4 fv_lo = w00f * ea0 + w01f * eb0 + w10f * ec0 + w11f * ed0;
    const f32x4 fv_hi = w00f * ea1 + w01f * eb1 + w10f * ec1 + w11f * ed1;

    const f32x4 e2 = (f32x4){4.f/9.f, 1.f/9.f, 1.f/9.f, 4.f/9.f};
    const f32x4 acc = e2 * (pv_lo * fv_lo + pv_hi * fv_hi);
    const float s = (acc.x + acc.y) + (acc.z + acc.w);

    // Fused damping: one exp per lane.
    const float bT2  = kn.z * (rqT * rqT);
    const float expo = -bT2 * (fmaf(kG2, lQ2, cn.x) - cn.y * lx + cn.z * (rz * rz));
    float val = s * __expf(expo) * kn.y;

    #pragma unroll
    for (int off = 32; off > 0; off >>= 1)
        val += __shfl_down(val, off, 64);

    if (lane == 0) {
        const float FUUT  = val * (rqT * rqT);
        const float alpha = kALPHA0 *
            frcp(1.0f - kALPHA0 / (3.0f * (float)M_PI) * (lQ2 - logf(kME2)));
        const float rQ    = frcp(Q);
        const float rx    = frcp(x);
        const float gamma = 2.0f * kM2 * x * rQ;
        const float y     = Q2 * rx * (1.0f / kSmM2);
        const float g2y2  = 0.25f * gamma * gamma * y * y;
        const float eps   = (1.0f - y - g2y2) *
                            frcp(1.0f - y + 0.5f * y * y + g2y2);
        const float pre   = 8.0f * (float)(M_PI * M_PI) * alpha * alpha
                          * z * z * qT * rx * (rQ * rQ * rQ)
                          * y * y * 0.5f * frcp(1.0f - eps)
                          * fmaf(gamma * gamma * 0.5f, rx, 1.0f);
        out[ev] = pre * FUUT;
    }
}

// ---- Fallback (only if ws_size too small): round-1 direct kernel ----
__global__ __launch_bounds__(256) void sidis_fwd_direct(
    const float* __restrict__ events,
    const float* __restrict__ pdfg,
    const float* __restrict__ ffg,
    const float* __restrict__ ogx,
    const float* __restrict__ ogw,
    const float* __restrict__ fnp,
    float* __restrict__ out)
{
    const int lane = threadIdx.x & 63;
    const int ev   = (blockIdx.x << 2) + (threadIdx.x >> 6);

    const float4 e = reinterpret_cast<const float4*>(events)[ev];
    const float x = e.x, PhT = e.y, Q = e.z, z = e.w;
    const float qT = PhT / z;
    const float Q2 = Q * Q;

    const float lam_p = log1pf(__expf(fnp[0]));
    const float lam_f = log1pf(__expf(fnp[1]));
    const float sig2  = 1.0f / (1.0f + __expf(-fnp[2]));
    const float sig3  = 1.0f / (1.0f + __expf(-fnp[3]));

    const float u_k = ogx[lane];
    const float w_k = ogw[lane];
    const float bT  = u_k / qT;
    const float lb  = __logf(bT);

    float fb = (lb - kLBMIN) * kScaleB;
    fb = fminf(fmaxf(fb, 0.0f), (float)(kNB - 1) - 1e-4f);
    const int   j0 = (int)fb;
    const float tb = fb - (float)j0;

    const float lx = __logf(x);
    float fxp = (lx - kLXMIN) * kScaleX;
    fxp = fminf(fmaxf(fxp, 0.0f), (float)(kNX - 1) - 1e-4f);
    const int   i0p = (int)fxp;
    const float txp = fxp - (float)i0p;

    const float lz = __logf(z);
    float fxf = (lz - kLXMIN) * kScaleX;
    fxf = fminf(fmaxf(fxf, 0.0f), (float)(kNX - 1) - 1e-4f);
    const int   i0f = (int)fxf;
    const float txf = fxf - (float)i0f;

    const float* pbase = pdfg + i0p * kNB + j0;
    const float* fbase = ffg  + i0f * kNB + j0;
    const float E2a[8] = {4.f/9, 1.f/9, 1.f/9, 4.f/9, 4.f/9, 1.f/9, 1.f/9, 4.f/9};

    float s = 0.0f;
    #pragma unroll
    for (int f = 0; f < 8; ++f) {
        const float* gp = pbase + f * kGridElems;
        const float p00 = gp[0], p01 = gp[1], p10 = gp[kNB], p11 = gp[kNB + 1];
        const float* gf = fbase + f * kGridElems;
        const float q00 = gf[0], q01 = gf[1], q10 = gf[kNB], q11 = gf[kNB + 1];
        const float pv = (1.0f - txp) * ((1.0f - tb) * p00 + tb * p01)
                       +          txp * ((1.0f - tb) * p10 + tb * p11);
        const float fv = (1.0f - txf) * ((1.0f - tb) * q00 + tb * q01)
                       +          txf * ((1.0f - tb) * q10 + tb * q11);
        s += E2a[f] * pv * fv;
    }

    const float bT2 = bT * bT;
    const float lQ2 = __logf(Q2);
    const float expo = -bT2 * (kG2 * lQ2
                               + lam_p * (1.0f - sig2 * lx)
                               + lam_f * (1.0f + sig3) / (z * z));
    float val = s * __expf(expo) * w_k;

    #pragma unroll
    for (int off = 32; off > 0; off >>= 1)
        val += __shfl_down(val, off, 64);

    if (lane == 0) {
        const float FUUT  = val / (qT * qT);
        const float alpha = kALPHA0 /
            (1.0f - kALPHA0 / (3.0f * (float)M_PI) * (lQ2 - logf(kME2)));
        const float gamma = 2.0f * kM2 * x / Q;
        const float y     = Q2 / (x * kSmM2);
        const float g2y2  = 0.25f * gamma * gamma * y * y;
        const float eps   = (1.0f - y - g2y2) /
                            (1.0f - y + 0.5f * y * y + g2y2);
        const float pre   = 8.0f * (float)(M_PI * M_PI) * alpha * alpha
                          * z * z * qT / x / (Q2 * Q)
                          * y * y * 0.5f / (1.0f - eps)
                          * (1.0f + gamma * gamma / (2.0f * x));
        out[ev] = pre * FUUT;
    }
}

extern "C" void kernel_launch(void* const* d_in, const int* in_sizes, int n_in,
                              void* d_out, int out_size, void* d_ws, size_t ws_size,
                              hipStream_t stream) {
    const float* events = (const float*)d_in[0];   // (65536, 4)
    const float* pdfg   = (const float*)d_in[1];   // (8, 256, 256)
    const float* ffg    = (const float*)d_in[2];   // (8, 256, 256)
    const float* ogx    = (const float*)d_in[3];   // (64,)
    const float* ogw    = (const float*)d_in[4];   // (64,)
    const float* fnp    = (const float*)d_in[5];   // (4,)
    float* out = (float*)d_out;

    const int    nev        = in_sizes[0] / 4;                        // 65536
    const size_t grid_elems = (size_t)kGridElems * 8;                 // floats
    const size_t need = (2 * grid_elems + 64 * 4 + 4) * sizeof(float);

    if (ws_size >= need) {
        float* wpdf  = (float*)d_ws;
        float* wff   = wpdf + grid_elems;
        float* knode = wff + grid_elems;          // 64 * float4
        float* cons  = knode + 64 * 4;            // float4
        interleave_grids<<<kGridElems / 256, 256, 0, stream>>>(pdfg, ffg, wpdf, wff);
        precompute_consts<<<1, 64, 0, stream>>>(ogx, ogw, fnp, knode, cons);
        sidis_fwd3<<<nev / 4, 256, 0, stream>>>(events, wpdf, wff, knode, cons, out);
    } else {
        sidis_fwd_direct<<<nev / 4, 256, 0, stream>>>(events, pdfg, ffg,
                                                      ogx, ogw, fnp, out);
    }
}

// Round 4
// 95.752 us; speedup vs baseline: 1.3288x; 1.1650x over previous
//
#include <hip/hip_runtime.h>
#include <math.h>

// SIDIS forward, round 4:
//  - grids repacked flavor-innermost AND fp16 (cell = 8 flavors x 2B = 16B)
//  - per-event precompute kernel hoists all wave-uniform math (logs, divides,
//    damping coefficient, epilogue prefactor, row offsets, tx weights)
//  - main kernel per lane: 1 FMA for fb, 8 gathers, packed-f16 bilinear,
//    1 mult + 1 exp for the damping, wave-64 reduce, 1 mult store.

namespace {
constexpr int   kNB    = 256;
constexpr int   kNX    = 256;
constexpr float kLXMIN = -9.210340371976182f;   // log(1e-4)
constexpr float kLBMIN = -6.907755278982137f;   // log(1e-3)
constexpr float kLBMAX =  3.912023005428146f;   // log(50)
constexpr float kScaleB = (float)(kNB - 1) / (kLBMAX - kLBMIN);
constexpr float kScaleX = (float)(kNX - 1) / (0.0f - kLXMIN);
constexpr float kG2    = 0.12f;
constexpr float kM2    = 0.8803f;
constexpr float kSmM2  = 140.0f - 0.8803f;      // S_MAND - M2
constexpr float kALPHA0 = 1.0f / 137.035999f;
constexpr float kME2   = 0.000511f * 0.000511f;
constexpr int   kGridElems = kNX * kNB;          // 65536 cells per flavor
}

typedef float    f32x4 __attribute__((ext_vector_type(4)));
typedef _Float16 f16x8 __attribute__((ext_vector_type(8)));

// ---- repack (8, NX, NB) fp32 -> (NX*NB, 8) fp16: 16B cells ----
__global__ __launch_bounds__(256) void interleave_grids_h(
    const float* __restrict__ pdfg, const float* __restrict__ ffg,
    _Float16* __restrict__ wpdf, _Float16* __restrict__ wff)
{
    const int idx = blockIdx.x * 256 + threadIdx.x;   // i*256 + j
    f16x8 p, q;
    #pragma unroll
    for (int f = 0; f < 8; ++f) {
        p[f] = (_Float16)pdfg[f * kGridElems + idx];
        q[f] = (_Float16)ffg [f * kGridElems + idx];
    }
    reinterpret_cast<f16x8*>(wpdf)[idx] = p;
    reinterpret_cast<f16x8*>(wff )[idx] = q;
}

// ---- per-Ogata-node constants: {log(u)*scaleB, W, u^2, 0} ----
__global__ __launch_bounds__(64) void precompute_nodes(
    const float* __restrict__ ogx, const float* __restrict__ ogw,
    float* __restrict__ knode)
{
    const int t = threadIdx.x;
    const float u = ogx[t];
    reinterpret_cast<f32x4*>(knode)[t] =
        (f32x4){logf(u) * kScaleB, ogw[t], u * u, 0.0f};
}

// ---- per-event constants (8 floats / event) ----
// evc[ev] = { fbofs, nD, scale, txp, txf, bits(prowByte), bits(frowByte), 0 }
__global__ __launch_bounds__(256) void precompute_events(
    const float* __restrict__ events,
    const float* __restrict__ fnp,
    float* __restrict__ evc)
{
    const int ev = blockIdx.x * 256 + threadIdx.x;
    const float4 e = reinterpret_cast<const float4*>(events)[ev];
    const float x = e.x, PhT = e.y, Q = e.z, z = e.w;

    const float lam_p = log1pf(expf(fnp[0]));
    const float lam_f = log1pf(expf(fnp[1]));
    const float sig2  = 1.0f / (1.0f + expf(-fnp[2]));
    const float sig3  = 1.0f / (1.0f + expf(-fnp[3]));

    const float qT  = PhT / z;
    const float rqT = z / PhT;
    const float Q2  = Q * Q;
    const float lx  = logf(x);
    const float lz  = logf(z);
    const float lqT = logf(qT);
    const float lQ2 = logf(Q2);

    // b-index offset: fb = log(u)*scaleB + fbofs
    const float fbofs = (-lqT - kLBMIN) * kScaleB;

    // x/z interp rows
    float fxp = (lx - kLXMIN) * kScaleX;
    fxp = fminf(fmaxf(fxp, 0.0f), (float)(kNX - 1) - 1e-4f);
    const int   i0p = (int)fxp;
    const float txp = fxp - (float)i0p;

    float fxf = (lz - kLXMIN) * kScaleX;
    fxf = fminf(fmaxf(fxf, 0.0f), (float)(kNX - 1) - 1e-4f);
    const int   i0f = (int)fxf;
    const float txf = fxf - (float)i0f;

    // combined damping coefficient: expo = -bT^2 * D = kn.u2 * nD
    const float D  = kG2 * lQ2
                   + lam_p * (1.0f - sig2 * lx)
                   + lam_f * (1.0f + sig3) / (z * z);
    const float nD = -(rqT * rqT) * D;

    // epilogue prefactor, folded with the /qT^2 of FUUT
    const float alpha = kALPHA0 /
        (1.0f - kALPHA0 / (3.0f * (float)M_PI) * logf(Q2 / kME2));
    const float gamma = 2.0f * kM2 * x / Q;
    const float y     = Q2 / (x * kSmM2);
    const float g2y2  = 0.25f * gamma * gamma * y * y;
    const float eps   = (1.0f - y - g2y2) /
                        (1.0f - y + 0.5f * y * y + g2y2);
    const float pre   = 8.0f * (float)(M_PI * M_PI) * alpha * alpha
                      * z * z * qT / x / (Q2 * Q)
                      * y * y * 0.5f / (1.0f - eps)
                      * (1.0f + gamma * gamma / (2.0f * x));
    const float scale = pre * rqT * rqT;

    const int prowByte = i0p * kNB * 16;   // 16B cells
    const int frowByte = i0f * kNB * 16;

    f32x4* dst = reinterpret_cast<f32x4*>(evc + (size_t)ev * 8);
    dst[0] = (f32x4){fbofs, nD, scale, txp};
    dst[1] = (f32x4){txf, __int_as_float(prowByte), __int_as_float(frowByte), 0.0f};
}

// ---- main: one wave per event, lane = Ogata node ----
__global__ __launch_bounds__(256) void sidis_fwd4(
    const float* __restrict__ evc,
    const _Float16* __restrict__ wpdf,
    const _Float16* __restrict__ wff,
    const float* __restrict__ knode,
    float* __restrict__ out)
{
    const int lane = threadIdx.x & 63;
    const int ev   = (blockIdx.x << 2) + (threadIdx.x >> 6);   // 4 waves/block

    const f32x4 c1 = reinterpret_cast<const f32x4*>(evc)[ev * 2];
    const f32x4 c2 = reinterpret_cast<const f32x4*>(evc)[ev * 2 + 1];
    const f32x4 kn = reinterpret_cast<const f32x4*>(knode)[lane];

    const float fbofs = c1.x, nD = c1.y, scale = c1.z;
    const _Float16 txph = (_Float16)c1.w;
    const _Float16 txfh = (_Float16)c2.x;
    const int prowByte = __builtin_amdgcn_readfirstlane(__float_as_int(c2.y));
    const int frowByte = __builtin_amdgcn_readfirstlane(__float_as_int(c2.z));

    float fb = kn.x + fbofs;
    fb = fminf(fmaxf(fb, 0.0f), (float)(kNB - 1) - 1e-4f);
    const int j0 = (int)fb;
    const _Float16 tbh = (_Float16)(fb - (float)j0);
    const int cell = j0 << 4;                       // 16B cells

    const char* pp0 = reinterpret_cast<const char*>(wpdf) + prowByte;
    const char* pp1 = pp0 + kNB * 16;
    const char* fp0 = reinterpret_cast<const char*>(wff) + frowByte;
    const char* fp1 = fp0 + kNB * 16;

    const f16x8 p00 = *reinterpret_cast<const f16x8*>(pp0 + cell);
    const f16x8 p01 = *reinterpret_cast<const f16x8*>(pp0 + cell + 16);
    const f16x8 p10 = *reinterpret_cast<const f16x8*>(pp1 + cell);
    const f16x8 p11 = *reinterpret_cast<const f16x8*>(pp1 + cell + 16);
    const f16x8 q00 = *reinterpret_cast<const f16x8*>(fp0 + cell);
    const f16x8 q01 = *reinterpret_cast<const f16x8*>(fp0 + cell + 16);
    const f16x8 q10 = *reinterpret_cast<const f16x8*>(fp1 + cell);
    const f16x8 q11 = *reinterpret_cast<const f16x8*>(fp1 + cell + 16);

    // packed-f16 bilinear
    const f16x8 pr0 = p00 + tbh * (p01 - p00);
    const f16x8 pr1 = p10 + tbh * (p11 - p10);
    const f16x8 pvh = pr0 + txph * (pr1 - pr0);
    const f16x8 qr0 = q00 + tbh * (q01 - q00);
    const f16x8 qr1 = q10 + tbh * (q11 - q10);
    const f16x8 fvh = qr0 + txfh * (qr1 - qr0);

    // convert to f32, e2-weighted dot
    const f32x4 pv_lo = {(float)pvh[0], (float)pvh[1], (float)pvh[2], (float)pvh[3]};
    const f32x4 pv_hi = {(float)pvh[4], (float)pvh[5], (float)pvh[6], (float)pvh[7]};
    const f32x4 fv_lo = {(float)fvh[0], (float)fvh[1], (float)fvh[2], (float)fvh[3]};
    const f32x4 fv_hi = {(float)fvh[4], (float)fvh[5], (float)fvh[6], (float)fvh[7]};

    const f32x4 e2 = (f32x4){4.f/9.f, 1.f/9.f, 1.f/9.f, 4.f/9.f};
    const f32x4 acc = e2 * (pv_lo * fv_lo + pv_hi * fv_hi);
    const float s = (acc.x + acc.y) + (acc.z + acc.w);

    // damping: one mult + one exp
    float val = s * __expf(kn.z * nD) * kn.y;

    #pragma unroll
    for (int off = 32; off > 0; off >>= 1)
        val += __shfl_down(val, off, 64);

    if (lane == 0)
        out[ev] = scale * val;
}

// ---- fallback (ws too small): round-1 direct kernel ----
__global__ __launch_bounds__(256) void sidis_fwd_direct(
    const float* __restrict__ events,
    const float* __restrict__ pdfg,
    const float* __restrict__ ffg,
    const float* __restrict__ ogx,
    const float* __restrict__ ogw,
    const float* __restrict__ fnp,
    float* __restrict__ out)
{
    const int lane = threadIdx.x & 63;
    const int ev   = (blockIdx.x << 2) + (threadIdx.x >> 6);

    const float4 e = reinterpret_cast<const float4*>(events)[ev];
    const float x = e.x, PhT = e.y, Q = e.z, z = e.w;
    const float qT = PhT / z;
    const float Q2 = Q * Q;

    const float lam_p = log1pf(__expf(fnp[0]));
    const float lam_f = log1pf(__expf(fnp[1]));
    const float sig2  = 1.0f / (1.0f + __expf(-fnp[2]));
    const float sig3  = 1.0f / (1.0f + __expf(-fnp[3]));

    const float u_k = ogx[lane];
    const float w_k = ogw[lane];
    const float bT  = u_k / qT;
    const float lb  = __logf(bT);

    float fb = (lb - kLBMIN) * kScaleB;
    fb = fminf(fmaxf(fb, 0.0f), (float)(kNB - 1) - 1e-4f);
    const int   j0 = (int)fb;
    const float tb = fb - (float)j0;

    const float lx = __logf(x);
    float fxp = (lx - kLXMIN) * kScaleX;
    fxp = fminf(fmaxf(fxp, 0.0f), (float)(kNX - 1) - 1e-4f);
    const int   i0p = (int)fxp;
    const float txp = fxp - (float)i0p;

    const float lz = __logf(z);
    float fxf = (lz - kLXMIN) * kScaleX;
    fxf = fminf(fmaxf(fxf, 0.0f), (float)(kNX - 1) - 1e-4f);
    const int   i0f = (int)fxf;
    const float txf = fxf - (float)i0f;

    const float* pbase = pdfg + i0p * kNB + j0;
    const float* fbase = ffg  + i0f * kNB + j0;
    const float E2a[8] = {4.f/9, 1.f/9, 1.f/9, 4.f/9, 4.f/9, 1.f/9, 1.f/9, 4.f/9};

    float s = 0.0f;
    #pragma unroll
    for (int f = 0; f < 8; ++f) {
        const float* gp = pbase + f * kGridElems;
        const float p00 = gp[0], p01 = gp[1], p10 = gp[kNB], p11 = gp[kNB + 1];
        const float* gf = fbase + f * kGridElems;
        const float q00 = gf[0], q01 = gf[1], q10 = gf[kNB], q11 = gf[kNB + 1];
        const float pv = (1.0f - txp) * ((1.0f - tb) * p00 + tb * p01)
                       +          txp * ((1.0f - tb) * p10 + tb * p11);
        const float fv = (1.0f - txf) * ((1.0f - tb) * q00 + tb * q01)
                       +          txf * ((1.0f - tb) * q10 + tb * q11);
        s += E2a[f] * pv * fv;
    }

    const float bT2 = bT * bT;
    const float lQ2 = __logf(Q2);
    const float expo = -bT2 * (kG2 * lQ2
                               + lam_p * (1.0f - sig2 * lx)
                               + lam_f * (1.0f + sig3) / (z * z));
    float val = s * __expf(expo) * w_k;

    #pragma unroll
    for (int off = 32; off > 0; off >>= 1)
        val += __shfl_down(val, off, 64);

    if (lane == 0) {
        const float FUUT  = val / (qT * qT);
        const float alpha = kALPHA0 /
            (1.0f - kALPHA0 / (3.0f * (float)M_PI) * (lQ2 - logf(kME2)));
        const float gamma = 2.0f * kM2 * x / Q;
        const float y     = Q2 / (x * kSmM2);
        const float g2y2  = 0.25f * gamma * gamma * y * y;
        const float eps   = (1.0f - y - g2y2) /
                            (1.0f - y + 0.5f * y * y + g2y2);
        const float pre   = 8.0f * (float)(M_PI * M_PI) * alpha * alpha
                          * z * z * qT / x / (Q2 * Q)
                          * y * y * 0.5f / (1.0f - eps)
                          * (1.0f + gamma * gamma / (2.0f * x));
        out[ev] = pre * FUUT;
    }
}

extern "C" void kernel_launch(void* const* d_in, const int* in_sizes, int n_in,
                              void* d_out, int out_size, void* d_ws, size_t ws_size,
                              hipStream_t stream) {
    const float* events = (const float*)d_in[0];   // (65536, 4)
    const float* pdfg   = (const float*)d_in[1];   // (8, 256, 256)
    const float* ffg    = (const float*)d_in[2];   // (8, 256, 256)
    const float* ogx    = (const float*)d_in[3];   // (64,)
    const float* ogw    = (const float*)d_in[4];   // (64,)
    const float* fnp    = (const float*)d_in[5];   // (4,)
    float* out = (float*)d_out;

    const int nev = in_sizes[0] / 4;               // 65536

    // ws layout: wpdf_h (1MB) | wff_h (1MB) | evc (2MB) | knode (1KB)
    const size_t gbytes = (size_t)kGridElems * 8 * sizeof(_Float16);  // 1 MB
    const size_t ebytes = (size_t)nev * 8 * sizeof(float);            // 2 MB
    const size_t need = 2 * gbytes + ebytes + 64 * 16;

    if (ws_size >= need) {
        char* base = (char*)d_ws;
        _Float16* wpdf  = (_Float16*)base;
        _Float16* wff   = (_Float16*)(base + gbytes);
        float*    evc   = (float*)(base + 2 * gbytes);
        float*    knode = (float*)(base + 2 * gbytes + ebytes);

        interleave_grids_h<<<kGridElems / 256, 256, 0, stream>>>(pdfg, ffg, wpdf, wff);
        precompute_nodes<<<1, 64, 0, stream>>>(ogx, ogw, knode);
        precompute_events<<<nev / 256, 256, 0, stream>>>(events, fnp, evc);
        sidis_fwd4<<<nev / 4, 256, 0, stream>>>(evc, wpdf, wff, knode, out);
    } else {
        sidis_fwd_direct<<<nev / 4, 256, 0, stream>>>(events, pdfg, ffg,
                                                      ogx, ogw, fnp, out);
    }
}

// Round 5
// 92.131 us; speedup vs baseline: 1.3810x; 1.0393x over previous
//
#include <hip/hip_runtime.h>
#include <math.h>

// SIDIS forward, round 5:
//  - ONE prep dispatch: fp16 flavor-innermost repack (E2 folded into pdf),
//    per-event constants (fast-math), per-node constants.
//  - main kernel: 1 FMA for fb, 8x16B gathers, packed-f16 bilinear, plain
//    dot (E2 pre-folded), one v_exp_f32 (log2e pre-folded), wave-64 reduce.

namespace {
constexpr int   kNB    = 256;
constexpr int   kNX    = 256;
constexpr float kLXMIN = -9.210340371976182f;   // log(1e-4)
constexpr float kLBMIN = -6.907755278982137f;   // log(1e-3)
constexpr float kLBMAX =  3.912023005428146f;   // log(50)
constexpr float kScaleB = (float)(kNB - 1) / (kLBMAX - kLBMIN);
constexpr float kScaleX = (float)(kNX - 1) / (0.0f - kLXMIN);
constexpr float kG2    = 0.12f;
constexpr float kM2    = 0.8803f;
constexpr float kSmM2  = 140.0f - 0.8803f;      // S_MAND - M2
constexpr float kALPHA0 = 1.0f / 137.035999f;
constexpr float kLogME2 = -14.858672703081717f; // log(0.000511^2)
constexpr float kLog2E  = 1.4426950408889634f;
constexpr int   kGridElems = kNX * kNB;          // 65536 cells per flavor
}

typedef float    f32x4 __attribute__((ext_vector_type(4)));
typedef _Float16 f16x8 __attribute__((ext_vector_type(8)));

__device__ __forceinline__ float frcp(float x) { return __builtin_amdgcn_rcpf(x); }

#if __has_builtin(__builtin_amdgcn_exp2f)
__device__ __forceinline__ float fexp2(float x) { return __builtin_amdgcn_exp2f(x); }
#else
__device__ __forceinline__ float fexp2(float x) { return __expf(x * 0.6931471805599453f); }
#endif

// ---- single prep dispatch: repack + event constants + node constants ----
// evc[ev] = { fbofs, nD2 (=-rqT^2*D*log2e), scale, txp | txf, prowByte, frowByte, 0 }
__global__ __launch_bounds__(256) void prep_all(
    const float* __restrict__ pdfg, const float* __restrict__ ffg,
    const float* __restrict__ events,
    const float* __restrict__ ogx, const float* __restrict__ ogw,
    const float* __restrict__ fnp,
    _Float16* __restrict__ wpdf, _Float16* __restrict__ wff,
    float* __restrict__ evc, float* __restrict__ knode)
{
    const int idx = blockIdx.x * 256 + threadIdx.x;   // cell idx == event idx

    // (a) grid repack, E2 folded into pdf (linear -> interp-equivalent)
    const float E2a[8] = {4.f/9, 1.f/9, 1.f/9, 4.f/9, 4.f/9, 1.f/9, 1.f/9, 4.f/9};
    f16x8 p, q;
    #pragma unroll
    for (int f = 0; f < 8; ++f) {
        p[f] = (_Float16)(pdfg[f * kGridElems + idx] * E2a[f]);
        q[f] = (_Float16)ffg[f * kGridElems + idx];
    }
    reinterpret_cast<f16x8*>(wpdf)[idx] = p;
    reinterpret_cast<f16x8*>(wff )[idx] = q;

    // (b) node constants (block 0, lanes 0-63)
    if (blockIdx.x == 0 && threadIdx.x < 64) {
        const float u = ogx[threadIdx.x];
        reinterpret_cast<f32x4*>(knode)[threadIdx.x] =
            (f32x4){__logf(u) * kScaleB, ogw[threadIdx.x], u * u, 0.0f};
    }

    // (c) per-event constants (fast-math)
    const float4 e = reinterpret_cast<const float4*>(events)[idx];
    const float x = e.x, PhT = e.y, Q = e.z, z = e.w;

    const float lam_p = log1pf(__expf(fnp[0]));
    const float lam_f = log1pf(__expf(fnp[1]));
    const float sig2  = frcp(1.0f + __expf(-fnp[2]));
    const float sig3  = frcp(1.0f + __expf(-fnp[3]));

    const float rz  = frcp(z);
    const float qT  = PhT * rz;
    const float rqT = z * frcp(PhT);
    const float Q2  = Q * Q;
    const float lx  = __logf(x);
    const float lz  = __logf(z);
    const float lqT = __logf(qT);
    const float lQ2 = 2.0f * __logf(Q);

    const float fbofs = (-lqT - kLBMIN) * kScaleB;

    float fxp = (lx - kLXMIN) * kScaleX;
    fxp = fminf(fmaxf(fxp, 0.0f), (float)(kNX - 1) - 1e-4f);
    const int   i0p = (int)fxp;
    const float txp = fxp - (float)i0p;

    float fxf = (lz - kLXMIN) * kScaleX;
    fxf = fminf(fmaxf(fxf, 0.0f), (float)(kNX - 1) - 1e-4f);
    const int   i0f = (int)fxf;
    const float txf = fxf - (float)i0f;

    const float D  = kG2 * lQ2
                   + lam_p * (1.0f - sig2 * lx)
                   + lam_f * (1.0f + sig3) * (rz * rz);
    const float nD2 = -(rqT * rqT) * D * kLog2E;     // exp2-ready

    const float alpha = kALPHA0 *
        frcp(1.0f - kALPHA0 / (3.0f * (float)M_PI) * (lQ2 - kLogME2));
    const float rQ    = frcp(Q);
    const float rx    = frcp(x);
    const float gamma = 2.0f * kM2 * x * rQ;
    const float y     = Q2 * rx * (1.0f / kSmM2);
    const float g2y2  = 0.25f * gamma * gamma * y * y;
    const float eps   = (1.0f - y - g2y2) *
                        frcp(1.0f - y + 0.5f * y * y + g2y2);
    const float pre   = 8.0f * (float)(M_PI * M_PI) * alpha * alpha
                      * z * z * qT * rx * (rQ * rQ * rQ)
                      * y * y * 0.5f * frcp(1.0f - eps)
                      * fmaf(gamma * gamma * 0.5f, rx, 1.0f);
    const float scale = pre * rqT * rqT;

    const int prowByte = i0p * kNB * 16;   // 16B cells
    const int frowByte = i0f * kNB * 16;

    f32x4* dst = reinterpret_cast<f32x4*>(evc + (size_t)idx * 8);
    dst[0] = (f32x4){fbofs, nD2, scale, txp};
    dst[1] = (f32x4){txf, __int_as_float(prowByte), __int_as_float(frowByte), 0.0f};
}

// ---- main: one wave per event, lane = Ogata node ----
__global__ __launch_bounds__(256) void sidis_fwd5(
    const float* __restrict__ evc,
    const _Float16* __restrict__ wpdf,
    const _Float16* __restrict__ wff,
    const float* __restrict__ knode,
    float* __restrict__ out)
{
    const int lane = threadIdx.x & 63;
    const int ev   = (blockIdx.x << 2) + (threadIdx.x >> 6);   // 4 waves/block

    const f32x4 c1 = reinterpret_cast<const f32x4*>(evc)[ev * 2];
    const f32x4 c2 = reinterpret_cast<const f32x4*>(evc)[ev * 2 + 1];
    const f32x4 kn = reinterpret_cast<const f32x4*>(knode)[lane];

    const float fbofs = c1.x, nD2 = c1.y, scale = c1.z;
    const _Float16 txph = (_Float16)c1.w;
    const _Float16 txfh = (_Float16)c2.x;
    const int prowByte = __builtin_amdgcn_readfirstlane(__float_as_int(c2.y));
    const int frowByte = __builtin_amdgcn_readfirstlane(__float_as_int(c2.z));

    float fb = kn.x + fbofs;
    fb = fminf(fmaxf(fb, 0.0f), (float)(kNB - 1) - 1e-4f);
    const int j0 = (int)fb;
    const _Float16 tbh = (_Float16)(fb - (float)j0);
    const int cell = j0 << 4;                       // 16B cells

    const char* pp0 = reinterpret_cast<const char*>(wpdf) + prowByte;
    const char* pp1 = pp0 + kNB * 16;
    const char* fp0 = reinterpret_cast<const char*>(wff) + frowByte;
    const char* fp1 = fp0 + kNB * 16;

    const f16x8 p00 = *reinterpret_cast<const f16x8*>(pp0 + cell);
    const f16x8 p01 = *reinterpret_cast<const f16x8*>(pp0 + cell + 16);
    const f16x8 p10 = *reinterpret_cast<const f16x8*>(pp1 + cell);
    const f16x8 p11 = *reinterpret_cast<const f16x8*>(pp1 + cell + 16);
    const f16x8 q00 = *reinterpret_cast<const f16x8*>(fp0 + cell);
    const f16x8 q01 = *reinterpret_cast<const f16x8*>(fp0 + cell + 16);
    const f16x8 q10 = *reinterpret_cast<const f16x8*>(fp1 + cell);
    const f16x8 q11 = *reinterpret_cast<const f16x8*>(fp1 + cell + 16);

    // packed-f16 bilinear (E2 already folded into pdf plane)
    const f16x8 pr0 = p00 + tbh * (p01 - p00);
    const f16x8 pr1 = p10 + tbh * (p11 - p10);
    const f16x8 pvh = pr0 + txph * (pr1 - pr0);
    const f16x8 qr0 = q00 + tbh * (q01 - q00);
    const f16x8 qr1 = q10 + tbh * (q11 - q10);
    const f16x8 fvh = qr0 + txfh * (qr1 - qr0);

    const f32x4 pv_lo = {(float)pvh[0], (float)pvh[1], (float)pvh[2], (float)pvh[3]};
    const f32x4 pv_hi = {(float)pvh[4], (float)pvh[5], (float)pvh[6], (float)pvh[7]};
    const f32x4 fv_lo = {(float)fvh[0], (float)fvh[1], (float)fvh[2], (float)fvh[3]};
    const f32x4 fv_hi = {(float)fvh[4], (float)fvh[5], (float)fvh[6], (float)fvh[7]};

    const f32x4 acc = pv_lo * fv_lo + pv_hi * fv_hi;
    const float s = (acc.x + acc.y) + (acc.z + acc.w);

    // damping: one mult + one v_exp_f32
    float val = s * fexp2(kn.z * nD2) * kn.y;

    #pragma unroll
    for (int off = 32; off > 0; off >>= 1)
        val += __shfl_down(val, off, 64);

    if (lane == 0)
        out[ev] = scale * val;
}

// ---- fallback (ws too small): direct kernel ----
__global__ __launch_bounds__(256) void sidis_fwd_direct(
    const float* __restrict__ events,
    const float* __restrict__ pdfg,
    const float* __restrict__ ffg,
    const float* __restrict__ ogx,
    const float* __restrict__ ogw,
    const float* __restrict__ fnp,
    float* __restrict__ out)
{
    const int lane = threadIdx.x & 63;
    const int ev   = (blockIdx.x << 2) + (threadIdx.x >> 6);

    const float4 e = reinterpret_cast<const float4*>(events)[ev];
    const float x = e.x, PhT = e.y, Q = e.z, z = e.w;
    const float qT = PhT / z;
    const float Q2 = Q * Q;

    const float lam_p = log1pf(__expf(fnp[0]));
    const float lam_f = log1pf(__expf(fnp[1]));
    const float sig2  = 1.0f / (1.0f + __expf(-fnp[2]));
    const float sig3  = 1.0f / (1.0f + __expf(-fnp[3]));

    const float u_k = ogx[lane];
    const float w_k = ogw[lane];
    const float bT  = u_k / qT;
    const float lb  = __logf(bT);

    float fb = (lb - kLBMIN) * kScaleB;
    fb = fminf(fmaxf(fb, 0.0f), (float)(kNB - 1) - 1e-4f);
    const int   j0 = (int)fb;
    const float tb = fb - (float)j0;

    const float lx = __logf(x);
    float fxp = (lx - kLXMIN) * kScaleX;
    fxp = fminf(fmaxf(fxp, 0.0f), (float)(kNX - 1) - 1e-4f);
    const int   i0p = (int)fxp;
    const float txp = fxp - (float)i0p;

    const float lz = __logf(z);
    float fxf = (lz - kLXMIN) * kScaleX;
    fxf = fminf(fmaxf(fxf, 0.0f), (float)(kNX - 1) - 1e-4f);
    const int   i0f = (int)fxf;
    const float txf = fxf - (float)i0f;

    const float* pbase = pdfg + i0p * kNB + j0;
    const float* fbase = ffg  + i0f * kNB + j0;
    const float E2a[8] = {4.f/9, 1.f/9, 1.f/9, 4.f/9, 4.f/9, 1.f/9, 1.f/9, 4.f/9};

    float s = 0.0f;
    #pragma unroll
    for (int f = 0; f < 8; ++f) {
        const float* gp = pbase + f * kGridElems;
        const float p00 = gp[0], p01 = gp[1], p10 = gp[kNB], p11 = gp[kNB + 1];
        const float* gf = fbase + f * kGridElems;
        const float q00 = gf[0], q01 = gf[1], q10 = gf[kNB], q11 = gf[kNB + 1];
        const float pv = (1.0f - txp) * ((1.0f - tb) * p00 + tb * p01)
                       +          txp * ((1.0f - tb) * p10 + tb * p11);
        const float fv = (1.0f - txf) * ((1.0f - tb) * q00 + tb * q01)
                       +          txf * ((1.0f - tb) * q10 + tb * q11);
        s += E2a[f] * pv * fv;
    }

    const float bT2 = bT * bT;
    const float lQ2 = __logf(Q2);
    const float expo = -bT2 * (kG2 * lQ2
                               + lam_p * (1.0f - sig2 * lx)
                               + lam_f * (1.0f + sig3) / (z * z));
    float val = s * __expf(expo) * w_k;

    #pragma unroll
    for (int off = 32; off > 0; off >>= 1)
        val += __shfl_down(val, off, 64);

    if (lane == 0) {
        const float FUUT  = val / (qT * qT);
        const float alpha = kALPHA0 /
            (1.0f - kALPHA0 / (3.0f * (float)M_PI) * (lQ2 - kLogME2));
        const float gamma = 2.0f * kM2 * x / Q;
        const float y     = Q2 / (x * kSmM2);
        const float g2y2  = 0.25f * gamma * gamma * y * y;
        const float eps   = (1.0f - y - g2y2) /
                            (1.0f - y + 0.5f * y * y + g2y2);
        const float pre   = 8.0f * (float)(M_PI * M_PI) * alpha * alpha
                          * z * z * qT / x / (Q2 * Q)
                          * y * y * 0.5f / (1.0f - eps)
                          * (1.0f + gamma * gamma / (2.0f * x));
        out[ev] = pre * FUUT;
    }
}

extern "C" void kernel_launch(void* const* d_in, const int* in_sizes, int n_in,
                              void* d_out, int out_size, void* d_ws, size_t ws_size,
                              hipStream_t stream) {
    const float* events = (const float*)d_in[0];   // (65536, 4)
    const float* pdfg   = (const float*)d_in[1];   // (8, 256, 256)
    const float* ffg    = (const float*)d_in[2];   // (8, 256, 256)
    const float* ogx    = (const float*)d_in[3];   // (64,)
    const float* ogw    = (const float*)d_in[4];   // (64,)
    const float* fnp    = (const float*)d_in[5];   // (4,)
    float* out = (float*)d_out;

    const int nev = in_sizes[0] / 4;               // 65536

    // ws layout: wpdf_h (1MB) | wff_h (1MB) | evc (2MB) | knode (1KB)
    const size_t gbytes = (size_t)kGridElems * 8 * sizeof(_Float16);  // 1 MB
    const size_t ebytes = (size_t)nev * 8 * sizeof(float);            // 2 MB
    const size_t need = 2 * gbytes + ebytes + 64 * 16;

    if (ws_size >= need && nev == kGridElems) {
        char* base = (char*)d_ws;
        _Float16* wpdf  = (_Float16*)base;
        _Float16* wff   = (_Float16*)(base + gbytes);
        float*    evc   = (float*)(base + 2 * gbytes);
        float*    knode = (float*)(base + 2 * gbytes + ebytes);

        prep_all<<<kGridElems / 256, 256, 0, stream>>>(
            pdfg, ffg, events, ogx, ogw, fnp, wpdf, wff, evc, knode);
        sidis_fwd5<<<nev / 4, 256, 0, stream>>>(evc, wpdf, wff, knode, out);
    } else {
        sidis_fwd_direct<<<nev / 4, 256, 0, stream>>>(events, pdfg, ffg,
                                                      ogx, ogw, fnp, out);
    }
}